// Round 13
// baseline (437.392 us; speedup 1.0000x reference)
//
#include <hip/hip_runtime.h>
#include <cstdint>
#include <cstddef>

#define BN_EPS 1e-5f
#define NCHUNK 256   // blocks in the edge-chunk partition (counting sort)
#define WT_PITCH 136 // bf16 elems per LDS Wt row (272B: 16B-aligned, bank-padded)

typedef short bf16x8 __attribute__((ext_vector_type(8)));
typedef float f32x4 __attribute__((ext_vector_type(4)));

// ---------------- helpers ----------------

__device__ __forceinline__ int edge_at(const void* e, long long i, int m64) {
  return m64 ? (int)((const long long*)e)[i] : ((const int*)e)[i];
}

__device__ __forceinline__ unsigned short f2bf(float f) {
  unsigned int u = __float_as_uint(f);
  unsigned int r = (u + 0x7FFFu + ((u >> 16) & 1u)) >> 16;
  return (unsigned short)r;
}

__device__ __forceinline__ unsigned int pack2bf(float lo, float hi) {
  return (unsigned int)f2bf(lo) | ((unsigned int)f2bf(hi) << 16);
}

// Detect int64 vs int32 edge_index
__global__ void detect_kernel(const int* __restrict__ e, int* __restrict__ mode) {
  int nz = 0;
  for (int i = 1; i < 512; i += 2) nz |= e[i];
  mode[0] = (nz == 0) ? 1 : 0;
}

// ---------------- contention-free counting sort by bucket ----------------

__global__ __launch_bounds__(256) void count_kernel(const void* __restrict__ edges,
                                                    const int* __restrict__ mode,
                                                    int* __restrict__ blockcounts,
                                                    int E, int nb, int chunk) {
  __shared__ int h[1024];
  int m = mode[0];
  for (int i = threadIdx.x; i < nb; i += 256) h[i] = 0;
  __syncthreads();
  long long lo = (long long)blockIdx.x * chunk;
  long long hi = lo + chunk;
  if (hi > E) hi = E;
  for (long long i = lo + threadIdx.x; i < hi; i += 256) {
    int c = edge_at(edges, (long long)E + i, m);
    atomicAdd(&h[c >> 8], 1);
  }
  __syncthreads();
  for (int j = threadIdx.x; j < nb; j += 256)
    blockcounts[(size_t)j * NCHUNK + blockIdx.x] = h[j];
}

// ---- generic hierarchical exclusive scan (4 elems/thread) ----
__global__ __launch_bounds__(256) void scan1_kernel(const int* __restrict__ src,
                                                    int* __restrict__ tprefix,
                                                    int* __restrict__ bsum, int n) {
  __shared__ int s[256];
  int t = threadIdx.x;
  int gid = blockIdx.x * 256 + t;
  int base = gid * 4;
  int sum = 0;
#pragma unroll
  for (int j = 0; j < 4; j++) {
    int i = base + j;
    if (i < n) sum += src[i];
  }
  s[t] = sum;
  __syncthreads();
  for (int off = 1; off < 256; off <<= 1) {
    int v = (t >= off) ? s[t - off] : 0;
    __syncthreads();
    s[t] += v;
    __syncthreads();
  }
  tprefix[gid] = s[t] - sum;
  if (t == 255) bsum[blockIdx.x] = s[255];
}

__global__ __launch_bounds__(256) void scan2_kernel(int* __restrict__ bsum, int nbk,
                                                    int* __restrict__ out, int n) {
  __shared__ int s[256];
  int t = threadIdx.x;
  int v = (t < nbk) ? bsum[t] : 0;
  s[t] = v;
  __syncthreads();
  for (int off = 1; off < 256; off <<= 1) {
    int u = (t >= off) ? s[t - off] : 0;
    __syncthreads();
    s[t] += u;
    __syncthreads();
  }
  if (t < nbk) bsum[t] = s[t] - v;
  if (t == 255) out[n] = s[255];
}

__global__ __launch_bounds__(256) void scan3_kernel(const int* __restrict__ src,
                                                    const int* __restrict__ tprefix,
                                                    const int* __restrict__ bsum,
                                                    int* __restrict__ out, int n) {
  int gid = blockIdx.x * 256 + threadIdx.x;
  int run = bsum[blockIdx.x] + tprefix[gid];
  int base = gid * 4;
#pragma unroll
  for (int j = 0; j < 4; j++) {
    int i = base + j;
    if (i < n) {
      int c = src[i];
      out[i] = run;
      run += c;
    }
  }
}

__global__ __launch_bounds__(256) void scatter_kernel(const void* __restrict__ edges,
                                                      const int* __restrict__ mode,
                                                      const int* __restrict__ moff,
                                                      int* __restrict__ pairs,
                                                      int E, int nb, int chunk) {
  __shared__ int cur[1024];
  int m = mode[0];
  for (int j = threadIdx.x; j < nb; j += 256)
    cur[j] = moff[(size_t)j * NCHUNK + blockIdx.x];
  __syncthreads();
  long long lo = (long long)blockIdx.x * chunk;
  long long hi = lo + chunk;
  if (hi > E) hi = E;
  for (long long i = lo + threadIdx.x; i < hi; i += 256) {
    int r = edge_at(edges, i, m);
    int c = edge_at(edges, (long long)E + i, m);
    int pos = atomicAdd(&cur[c >> 8], 1);
    pairs[pos] = (r << 8) | (c & 255);
  }
}

// merged per-bucket finalize: histogram -> dinv + offsets -> CSR fill
__global__ __launch_bounds__(256) void passB12_kernel(const int* __restrict__ pairs,
                                                      const int* __restrict__ moff,
                                                      float* __restrict__ dinv,
                                                      int* __restrict__ offsets,
                                                      int* __restrict__ csr_row, int n) {
  __shared__ int h[256];
  __shared__ int s[256];
  int t = threadIdx.x;
  int b = blockIdx.x;
  h[t] = 0;
  __syncthreads();
  int lo = moff[(size_t)b * NCHUNK];
  int hi = moff[(size_t)(b + 1) * NCHUNK];
  for (int e = lo + t; e < hi; e += 256)
    atomicAdd(&h[pairs[e] & 255], 1);
  __syncthreads();
  int d = h[t];
  s[t] = d;
  __syncthreads();
  for (int off = 1; off < 256; off <<= 1) {
    int v = (t >= off) ? s[t - off] : 0;
    __syncthreads();
    s[t] += v;
    __syncthreads();
  }
  int start = lo + s[t] - d;
  int node = b * 256 + t;
  if (node < n) {
    offsets[node] = start;
    dinv[node] = d > 0 ? rsqrtf((float)d) : 0.f;
    if (node == n - 1) offsets[n] = hi;
  }
  s[t] = start;  // reuse as cursor
  __syncthreads();
  for (int e = lo + t; e < hi; e += 256) {
    int p = pairs[e];
    int pos = atomicAdd(&s[p & 255], 1);
    csr_row[pos] = p >> 8;
  }
}

// ---------------- degree-sort nodes (counting sort, 128 bins) ----------------
// Groups near-equal-degree nodes into the same wave in agg (wave balance).
__global__ __launch_bounds__(256) void dsort1_kernel(const int* __restrict__ offsets,
                                                     int* __restrict__ dbc, int n, int nb) {
  __shared__ int h[128];
  int t = threadIdx.x, b = blockIdx.x;
  if (t < 128) h[t] = 0;
  __syncthreads();
  int node = b * 256 + t;
  if (node < n) {
    int d = offsets[node + 1] - offsets[node];
    int bin = d > 127 ? 127 : d;
    atomicAdd(&h[bin], 1);
  }
  __syncthreads();
  if (t < 128) dbc[(size_t)t * nb + b] = h[t];
}

__global__ __launch_bounds__(256) void dsort2_kernel(const int* __restrict__ offsets,
                                                     const int* __restrict__ dpos,
                                                     int* __restrict__ perm, int n, int nb) {
  __shared__ int cur[128];
  int t = threadIdx.x, b = blockIdx.x;
  if (t < 128) cur[t] = dpos[(size_t)t * nb + b];
  __syncthreads();
  int node = b * 256 + t;
  if (node < n) {
    int d = offsets[node + 1] - offsets[node];
    int bin = d > 127 ? 127 : d;
    int pos = atomicAdd(&cur[bin], 1);
    perm[pos] = node;
  }
}

// ---------------- per-layer prep: BN finalize + fold affine into W ----------------
__global__ __launch_bounds__(256) void prepWR_kernel(const float* __restrict__ W,
                                                     const float* __restrict__ colstats,
                                                     const float* __restrict__ gamma,
                                                     const float* __restrict__ beta,
                                                     float invN, int use_affine,
                                                     unsigned short* __restrict__ Wt,
                                                     float* __restrict__ rbias) {
  __shared__ float sc[128], sh[128];
  int t = threadIdx.x;
  if (t < 128) {
    float scv = 1.f, shv = 0.f;
    if (use_affine) {
      float mu = colstats[t] * invN;
      float var = colstats[128 + t] * invN - mu * mu;
      var = fmaxf(var, 0.f);
      scv = gamma[t] * rsqrtf(var + BN_EPS);
      shv = beta[t] - mu * scv;
    }
    sc[t] = scv;
    sh[t] = shv;
  }
  __syncthreads();
  int idx = blockIdx.x * 256 + t;
  int nc = idx >> 7, k = idx & 127;
  Wt[(size_t)nc * 128 + k] = f2bf(W[(size_t)k * 128 + nc] * sc[k]);
  if (blockIdx.x == 0 && t < 128) {
    float s = 0.f;
    if (use_affine) {
      for (int kk = 0; kk < 128; kk++) s += sh[kk] * W[(size_t)kk * 128 + t];
    }
    rbias[t] = s;
  }
}

// ---------------- MFMA GEMM (swapped operands, LDS-staged Wt) ----------------
template <int A_IS_FP32>
__global__ __launch_bounds__(256) void gemm_mfma_kernel(
    const void* __restrict__ Ain, const unsigned short* __restrict__ Wt,
    const float* __restrict__ rbias, const float* __restrict__ dinv,
    unsigned short* __restrict__ xb, int n) {
  __shared__ unsigned short wt[128 * WT_PITCH];
  int t = threadIdx.x;
  {
    int row = t >> 1, half = t & 1;
    const uint4* src = (const uint4*)(Wt + (size_t)row * 128 + half * 64);
    uint4* dst = (uint4*)(wt + row * WT_PITCH + half * 64);
#pragma unroll
    for (int j = 0; j < 8; j++) dst[j] = src[j];
  }
  __syncthreads();

  int l = t & 63;
  int w = t >> 6;
  int row0 = blockIdx.x * 64 + w * 16;
  int m = row0 + (l & 15);
  int mc = m < n ? m : n - 1;
  int kg = l >> 4;

  bf16x8 b[4];
#pragma unroll
  for (int kk = 0; kk < 4; kk++) {
    if (A_IS_FP32) {
      const float* ap = (const float*)Ain + (size_t)mc * 128 + kk * 32 + kg * 8;
      float4 f0 = *(const float4*)ap;
      float4 f1 = *(const float4*)(ap + 4);
      bf16x8 bb;
      bb[0] = (short)f2bf(f0.x); bb[1] = (short)f2bf(f0.y);
      bb[2] = (short)f2bf(f0.z); bb[3] = (short)f2bf(f0.w);
      bb[4] = (short)f2bf(f1.x); bb[5] = (short)f2bf(f1.y);
      bb[6] = (short)f2bf(f1.z); bb[7] = (short)f2bf(f1.w);
      b[kk] = bb;
    } else {
      b[kk] = *(const bf16x8*)((const unsigned short*)Ain + (size_t)mc * 128 + kk * 32 + kg * 8);
    }
  }

  f32x4 acc[8];
#pragma unroll
  for (int nt = 0; nt < 8; nt++) {
    f32x4 zv = {0.f, 0.f, 0.f, 0.f};
    acc[nt] = zv;
  }

#pragma unroll
  for (int kk = 0; kk < 4; kk++) {
#pragma unroll
    for (int nt = 0; nt < 8; nt++) {
      bf16x8 a = *(const bf16x8*)(wt + (size_t)(nt * 16 + (l & 15)) * WT_PITCH + kk * 32 + kg * 8);
      acc[nt] = __builtin_amdgcn_mfma_f32_16x16x32_bf16(a, b[kk], acc[nt], 0, 0, 0);
    }
  }

  float dv = dinv[mc];
  int colbase = kg * 4;
#pragma unroll
  for (int nt = 0; nt < 8; nt++) {
    int c0 = nt * 16 + colbase;
    float4 rb = *(const float4*)&rbias[c0];
    unsigned int w0 = pack2bf((acc[nt][0] + rb.x) * dv, (acc[nt][1] + rb.y) * dv);
    unsigned int w1 = pack2bf((acc[nt][2] + rb.z) * dv, (acc[nt][3] + rb.w) * dv);
    if (m < n)
      *(uint2*)(xb + (size_t)m * 128 + c0) = make_uint2(w0, w1);
  }
}

// ---------------- aggregation: z[c] = dinv[c] * sum_in xb[row] ----------------
// Round-8-proven body + degree-sorted node order (perm) for wave balance.
template <int F32OUT>
__global__ __launch_bounds__(256) void agg_kernel(
    const uint4* __restrict__ x4, const int* __restrict__ csr_row,
    const int* __restrict__ offsets, const float* __restrict__ dinv,
    const int* __restrict__ perm, void* __restrict__ z, int n) {
  int slot = blockIdx.x * 16 + (threadIdx.x >> 4);
  int d8 = threadIdx.x & 15;  // 8 bf16 per lane
  if (slot >= n) return;
  int node = perm[slot];
  int lo = offsets[node], hi = offsets[node + 1];
  float a0[8] = {}, a1[8] = {}, a2[8] = {}, a3[8] = {};
#define ACC8(A, v)                                                         \
  A[0] += __uint_as_float((v).x << 16); A[1] += __uint_as_float((v).x & 0xffff0000u); \
  A[2] += __uint_as_float((v).y << 16); A[3] += __uint_as_float((v).y & 0xffff0000u); \
  A[4] += __uint_as_float((v).z << 16); A[5] += __uint_as_float((v).z & 0xffff0000u); \
  A[6] += __uint_as_float((v).w << 16); A[7] += __uint_as_float((v).w & 0xffff0000u);
  int e = lo;
  for (; e + 4 <= hi; e += 4) {
    int r0 = csr_row[e];
    int r1 = csr_row[e + 1];
    int r2 = csr_row[e + 2];
    int r3 = csr_row[e + 3];
    uint4 v0 = x4[(size_t)r0 * 16 + d8];
    uint4 v1 = x4[(size_t)r1 * 16 + d8];
    uint4 v2 = x4[(size_t)r2 * 16 + d8];
    uint4 v3 = x4[(size_t)r3 * 16 + d8];
    ACC8(a0, v0) ACC8(a1, v1) ACC8(a2, v2) ACC8(a3, v3)
  }
  for (; e < hi; e++) {
    uint4 v = x4[(size_t)csr_row[e] * 16 + d8];
    ACC8(a0, v)
  }
#undef ACC8
  float dvn = dinv[node];
  float s[8];
#pragma unroll
  for (int j = 0; j < 8; j++) s[j] = (a0[j] + a1[j] + a2[j] + a3[j]) * dvn;
  if (F32OUT) {
    float* zp = (float*)z + (size_t)node * 128 + d8 * 8;
    *(float4*)zp = make_float4(s[0], s[1], s[2], s[3]);
    *(float4*)(zp + 4) = make_float4(s[4], s[5], s[6], s[7]);
  } else {
    uint4 o = make_uint4(pack2bf(s[0], s[1]), pack2bf(s[2], s[3]),
                         pack2bf(s[4], s[5]), pack2bf(s[6], s[7]));
    *(uint4*)((unsigned short*)z + (size_t)node * 128 + d8 * 8) = o;
  }
}

// ---------------- vectorized BN stats (streaming, balanced) ----------------
template <int F32IN>
__global__ __launch_bounds__(256) void stats2_kernel(
    const void* __restrict__ z, float* __restrict__ partial, int total8) {
  __shared__ float ps[256];  // [0:128) colsum, [128:256) colsumsq
  int t = threadIdx.x;
  ps[t] = 0.f;
  __syncthreads();
  int d8 = t & 15;
  float s[8] = {}, q[8] = {};
  int idx = blockIdx.x * 256 + t;
  int stride = gridDim.x * 256;  // multiple of 16 -> column group invariant
  for (int i = idx; i < total8; i += stride) {
    float v[8];
    if (F32IN) {
      const float* zp = (const float*)z + (size_t)i * 8;
      float4 f0 = *(const float4*)zp;
      float4 f1 = *(const float4*)(zp + 4);
      v[0] = f0.x; v[1] = f0.y; v[2] = f0.z; v[3] = f0.w;
      v[4] = f1.x; v[5] = f1.y; v[6] = f1.z; v[7] = f1.w;
    } else {
      uint4 u = ((const uint4*)z)[i];
      v[0] = __uint_as_float(u.x << 16); v[1] = __uint_as_float(u.x & 0xffff0000u);
      v[2] = __uint_as_float(u.y << 16); v[3] = __uint_as_float(u.y & 0xffff0000u);
      v[4] = __uint_as_float(u.z << 16); v[5] = __uint_as_float(u.z & 0xffff0000u);
      v[6] = __uint_as_float(u.w << 16); v[7] = __uint_as_float(u.w & 0xffff0000u);
    }
#pragma unroll
    for (int j = 0; j < 8; j++) { s[j] += v[j]; q[j] += v[j] * v[j]; }
  }
#pragma unroll
  for (int j = 0; j < 8; j++) {
    atomicAdd(&ps[d8 * 8 + j], s[j]);
    atomicAdd(&ps[128 + d8 * 8 + j], q[j]);
  }
  __syncthreads();
  partial[(size_t)blockIdx.x * 256 + t] = ps[t];
}

// reduce per-block partials -> colstats (colsum[0:128] ++ colsumsq[128:256])
__global__ __launch_bounds__(256) void reduce_stats_kernel(
    const float* __restrict__ partial, float* __restrict__ out, int nblk) {
  __shared__ float red[256];
  int c = blockIdx.x;  // 0..255
  float s = 0.f;
  for (int i = threadIdx.x; i < nblk; i += 256) s += partial[(size_t)i * 256 + c];
  red[threadIdx.x] = s;
  __syncthreads();
  for (int o = 128; o > 0; o >>= 1) {
    if (threadIdx.x < o) red[threadIdx.x] += red[threadIdx.x + o];
    __syncthreads();
  }
  if (threadIdx.x == 0) out[c] = red[0];
}

// in-place fp32 BN on d_out (layer 2): finalize folded in (per-block LDS)
__global__ __launch_bounds__(256) void norm_kernel(
    float* __restrict__ z, const float* __restrict__ colstats,
    const float* __restrict__ gamma, const float* __restrict__ beta,
    float invN, int total4) {
  __shared__ float sc[128], sh[128];
  int t = threadIdx.x;
  if (t < 128) {
    float mu = colstats[t] * invN;
    float var = colstats[128 + t] * invN - mu * mu;
    var = fmaxf(var, 0.f);
    float s = gamma[t] * rsqrtf(var + BN_EPS);
    sc[t] = s;
    sh[t] = beta[t] - mu * s;
  }
  __syncthreads();
  int idx = blockIdx.x * blockDim.x + t;
  int stride = gridDim.x * blockDim.x;
  for (int i = idx; i < total4; i += stride) {
    float4 v = ((const float4*)z)[i];
    int d0 = (i & 31) * 4;
    v.x = v.x * sc[d0] + sh[d0];
    v.y = v.y * sc[d0 + 1] + sh[d0 + 1];
    v.z = v.z * sc[d0 + 2] + sh[d0 + 2];
    v.w = v.w * sc[d0 + 3] + sh[d0 + 3];
    ((float4*)z)[i] = v;
  }
}

// ---------------- launcher ----------------

extern "C" void kernel_launch(void* const* d_in, const int* in_sizes, int n_in,
                              void* d_out, int out_size, void* d_ws, size_t ws_size,
                              hipStream_t stream) {
  const float* feats = (const float*)d_in[0];
  const void* edges = d_in[1];
  const float* W = (const float*)d_in[2];
  const float* gamma = (const float*)d_in[4];
  const float* beta = (const float*)d_in[5];

  const int n = in_sizes[0] / 128;
  const int E = in_sizes[1] / 2;

  const int nb = (n + 255) / 256;
  const int m = nb * NCHUNK;
  const int m2 = 128 * nb;  // degree-sort count matrix
  const int chunk = (E + NCHUNK - 1) / NCHUNK;
  const int sb_m = (m + 1023) / 1024;
  const int sb_m2 = (m2 + 1023) / 1024;
  const int nagg = (n + 15) / 16;
  const int nstat = 1024;

  char* ws = (char*)d_ws;
  size_t off = 0;
  unsigned short* xb = (unsigned short*)(ws + off); off += (size_t)n * 128 * 2; off = (off + 255) & ~(size_t)255;
  float* dinv = (float*)(ws + off); off += (size_t)n * 4;
  int* offsets = (int*)(ws + off); off += (size_t)(n + 1) * 4; off = (off + 255) & ~(size_t)255;
  int* csr_row = (int*)(ws + off); off += (size_t)E * 4; off = (off + 255) & ~(size_t)255;
  int* pairs = (int*)(ws + off); off += (size_t)E * 4; off = (off + 255) & ~(size_t)255;
  int* blockcounts = (int*)(ws + off); off += (size_t)m * 4; off = (off + 255) & ~(size_t)255;
  int* moff = (int*)(ws + off); off += (size_t)(m + 1) * 4; off = (off + 255) & ~(size_t)255;
  int* tprefix = (int*)(ws + off); off += (size_t)sb_m * 256 * 4; off = (off + 255) & ~(size_t)255;
  int* bsum = (int*)(ws + off); off += 256 * 4;
  int* perm = (int*)(ws + off); off += (size_t)n * 4; off = (off + 255) & ~(size_t)255;
  int* dbc = (int*)(ws + off); off += (size_t)m2 * 4; off = (off + 255) & ~(size_t)255;
  int* dpos = (int*)(ws + off); off += (size_t)(m2 + 1) * 4; off = (off + 255) & ~(size_t)255;
  unsigned short* Wt = (unsigned short*)(ws + off); off += 128 * 128 * 2; off = (off + 255) & ~(size_t)255;
  float* rbias = (float*)(ws + off); off += 128 * 4;
  float* colstats = (float*)(ws + off); off += 256 * 4;
  int* mode = (int*)(ws + off); off += 4;

  // pairs is dead after CSR build; reuse as the stats-partial buffer (1 MB used)
  float* partial = (float*)pairs;

  // ---- contention-free CSR build (graph is layer-invariant) ----
  detect_kernel<<<1, 1, 0, stream>>>((const int*)edges, mode);
  count_kernel<<<NCHUNK, 256, 0, stream>>>(edges, mode, blockcounts, E, nb, chunk);
  scan1_kernel<<<sb_m, 256, 0, stream>>>(blockcounts, tprefix, bsum, m);
  scan2_kernel<<<1, 256, 0, stream>>>(bsum, sb_m, moff, m);
  scan3_kernel<<<sb_m, 256, 0, stream>>>(blockcounts, tprefix, bsum, moff, m);
  scatter_kernel<<<NCHUNK, 256, 0, stream>>>(edges, mode, moff, pairs, E, nb, chunk);
  passB12_kernel<<<nb, 256, 0, stream>>>(pairs, moff, dinv, offsets, csr_row, n);
  // degree-sort nodes for agg wave balance
  dsort1_kernel<<<nb, 256, 0, stream>>>(offsets, dbc, n, nb);
  scan1_kernel<<<sb_m2, 256, 0, stream>>>(dbc, tprefix, bsum, m2);
  scan2_kernel<<<1, 256, 0, stream>>>(bsum, sb_m2, dpos, m2);
  scan3_kernel<<<sb_m2, 256, 0, stream>>>(dbc, tprefix, bsum, dpos, m2);
  dsort2_kernel<<<nb, 256, 0, stream>>>(offsets, dpos, perm, n, nb);

  unsigned short* zb = (unsigned short*)d_out;  // bf16 z (layers 0,1)
  float* zf = (float*)d_out;                    // fp32 z (layer 2)
  const int ggrid = (n + 63) / 64;
  const int total8 = n * 16;
  const float invN = 1.0f / (float)n;

  for (int l = 0; l < 3; l++) {
    prepWR_kernel<<<64, 256, 0, stream>>>(W + (size_t)l * 16384, colstats,
                                          gamma + l * 128, beta + l * 128, invN,
                                          l > 0 ? 1 : 0, Wt, rbias);
    if (l == 0)
      gemm_mfma_kernel<1><<<ggrid, 256, 0, stream>>>(feats, Wt, rbias, dinv, xb, n);
    else
      gemm_mfma_kernel<0><<<ggrid, 256, 0, stream>>>(zb, Wt, rbias, dinv, xb, n);
    if (l < 2) {
      agg_kernel<0><<<nagg, 256, 0, stream>>>(
          (const uint4*)xb, csr_row, offsets, dinv, perm, zb, n);
      stats2_kernel<0><<<nstat, 256, 0, stream>>>(zb, partial, total8);
    } else {
      agg_kernel<1><<<nagg, 256, 0, stream>>>(
          (const uint4*)xb, csr_row, offsets, dinv, perm, zf, n);
      stats2_kernel<1><<<nstat, 256, 0, stream>>>(zf, partial, total8);
    }
    reduce_stats_kernel<<<256, 256, 0, stream>>>(partial, colstats, nstat);
  }
  norm_kernel<<<2048, 256, 0, stream>>>(zf, colstats, gamma + 2 * 128, beta + 2 * 128,
                                        invN, (n * 128) / 4);
}

// Round 14
// 417.465 us; speedup vs baseline: 1.0477x; 1.0477x over previous
//
#include <hip/hip_runtime.h>
#include <cstdint>
#include <cstddef>

#define BN_EPS 1e-5f
#define NCHUNK 256   // blocks in the edge-chunk partition (counting sort)
#define WT_PITCH 136 // bf16 elems per LDS Wt row (272B: 16B-aligned, bank-padded)

typedef short bf16x8 __attribute__((ext_vector_type(8)));
typedef float f32x4 __attribute__((ext_vector_type(4)));

// ---------------- helpers ----------------

__device__ __forceinline__ int edge_at(const void* e, long long i, int m64) {
  return m64 ? (int)((const long long*)e)[i] : ((const int*)e)[i];
}

__device__ __forceinline__ unsigned short f2bf(float f) {
  unsigned int u = __float_as_uint(f);
  unsigned int r = (u + 0x7FFFu + ((u >> 16) & 1u)) >> 16;
  return (unsigned short)r;
}

__device__ __forceinline__ unsigned int pack2bf(float lo, float hi) {
  return (unsigned int)f2bf(lo) | ((unsigned int)f2bf(hi) << 16);
}

// Detect int64 vs int32 edge_index
__global__ void detect_kernel(const int* __restrict__ e, int* __restrict__ mode) {
  int nz = 0;
  for (int i = 1; i < 512; i += 2) nz |= e[i];
  mode[0] = (nz == 0) ? 1 : 0;
}

// ---------------- contention-free counting sort by bucket ----------------

__global__ __launch_bounds__(256) void count_kernel(const void* __restrict__ edges,
                                                    const int* __restrict__ mode,
                                                    int* __restrict__ blockcounts,
                                                    int E, int nb, int chunk) {
  __shared__ int h[1024];
  int m = mode[0];
  for (int i = threadIdx.x; i < nb; i += 256) h[i] = 0;
  __syncthreads();
  long long lo = (long long)blockIdx.x * chunk;
  long long hi = lo + chunk;
  if (hi > E) hi = E;
  for (long long i = lo + threadIdx.x; i < hi; i += 256) {
    int c = edge_at(edges, (long long)E + i, m);
    atomicAdd(&h[c >> 8], 1);
  }
  __syncthreads();
  for (int j = threadIdx.x; j < nb; j += 256)
    blockcounts[(size_t)j * NCHUNK + blockIdx.x] = h[j];
}

// ---- generic hierarchical exclusive scan (4 elems/thread), used for moff ----
__global__ __launch_bounds__(256) void scan1_kernel(const int* __restrict__ src,
                                                    int* __restrict__ tprefix,
                                                    int* __restrict__ bsum, int n) {
  __shared__ int s[256];
  int t = threadIdx.x;
  int gid = blockIdx.x * 256 + t;
  int base = gid * 4;
  int sum = 0;
#pragma unroll
  for (int j = 0; j < 4; j++) {
    int i = base + j;
    if (i < n) sum += src[i];
  }
  s[t] = sum;
  __syncthreads();
  for (int off = 1; off < 256; off <<= 1) {
    int v = (t >= off) ? s[t - off] : 0;
    __syncthreads();
    s[t] += v;
    __syncthreads();
  }
  tprefix[gid] = s[t] - sum;
  if (t == 255) bsum[blockIdx.x] = s[255];
}

__global__ __launch_bounds__(256) void scan2_kernel(int* __restrict__ bsum, int nbk,
                                                    int* __restrict__ out, int n) {
  __shared__ int s[256];
  int t = threadIdx.x;
  int v = (t < nbk) ? bsum[t] : 0;
  s[t] = v;
  __syncthreads();
  for (int off = 1; off < 256; off <<= 1) {
    int u = (t >= off) ? s[t - off] : 0;
    __syncthreads();
    s[t] += u;
    __syncthreads();
  }
  if (t < nbk) bsum[t] = s[t] - v;
  if (t == 255) out[n] = s[255];
}

__global__ __launch_bounds__(256) void scan3_kernel(const int* __restrict__ src,
                                                    const int* __restrict__ tprefix,
                                                    const int* __restrict__ bsum,
                                                    int* __restrict__ out, int n) {
  int gid = blockIdx.x * 256 + threadIdx.x;
  int run = bsum[blockIdx.x] + tprefix[gid];
  int base = gid * 4;
#pragma unroll
  for (int j = 0; j < 4; j++) {
    int i = base + j;
    if (i < n) {
      int c = src[i];
      out[i] = run;
      run += c;
    }
  }
}

__global__ __launch_bounds__(256) void scatter_kernel(const void* __restrict__ edges,
                                                      const int* __restrict__ mode,
                                                      const int* __restrict__ moff,
                                                      int* __restrict__ pairs,
                                                      int E, int nb, int chunk) {
  __shared__ int cur[1024];
  int m = mode[0];
  for (int j = threadIdx.x; j < nb; j += 256)
    cur[j] = moff[(size_t)j * NCHUNK + blockIdx.x];
  __syncthreads();
  long long lo = (long long)blockIdx.x * chunk;
  long long hi = lo + chunk;
  if (hi > E) hi = E;
  for (long long i = lo + threadIdx.x; i < hi; i += 256) {
    int r = edge_at(edges, i, m);
    int c = edge_at(edges, (long long)E + i, m);
    int pos = atomicAdd(&cur[c >> 8], 1);
    pairs[pos] = (r << 8) | (c & 255);
  }
}

// merged per-bucket finalize: histogram -> dinv + offsets -> CSR fill
__global__ __launch_bounds__(256) void passB12_kernel(const int* __restrict__ pairs,
                                                      const int* __restrict__ moff,
                                                      float* __restrict__ dinv,
                                                      int* __restrict__ offsets,
                                                      int* __restrict__ csr_row, int n) {
  __shared__ int h[256];
  __shared__ int s[256];
  int t = threadIdx.x;
  int b = blockIdx.x;
  h[t] = 0;
  __syncthreads();
  int lo = moff[(size_t)b * NCHUNK];
  int hi = moff[(size_t)(b + 1) * NCHUNK];
  for (int e = lo + t; e < hi; e += 256)
    atomicAdd(&h[pairs[e] & 255], 1);
  __syncthreads();
  int d = h[t];
  s[t] = d;
  __syncthreads();
  for (int off = 1; off < 256; off <<= 1) {
    int v = (t >= off) ? s[t - off] : 0;
    __syncthreads();
    s[t] += v;
    __syncthreads();
  }
  int start = lo + s[t] - d;
  int node = b * 256 + t;
  if (node < n) {
    offsets[node] = start;
    dinv[node] = d > 0 ? rsqrtf((float)d) : 0.f;
    if (node == n - 1) offsets[n] = hi;
  }
  s[t] = start;  // reuse as cursor
  __syncthreads();
  for (int e = lo + t; e < hi; e += 256) {
    int p = pairs[e];
    int pos = atomicAdd(&s[p & 255], 1);
    csr_row[pos] = p >> 8;
  }
}

// ---------------- per-layer prep: BN finalize + fold affine into W ----------------
__global__ __launch_bounds__(256) void prepWR_kernel(const float* __restrict__ W,
                                                     const float* __restrict__ colstats,
                                                     const float* __restrict__ gamma,
                                                     const float* __restrict__ beta,
                                                     float invN, int use_affine,
                                                     unsigned short* __restrict__ Wt,
                                                     float* __restrict__ rbias) {
  __shared__ float sc[128], sh[128];
  int t = threadIdx.x;
  if (t < 128) {
    float scv = 1.f, shv = 0.f;
    if (use_affine) {
      float mu = colstats[t] * invN;
      float var = colstats[128 + t] * invN - mu * mu;
      var = fmaxf(var, 0.f);
      scv = gamma[t] * rsqrtf(var + BN_EPS);
      shv = beta[t] - mu * scv;
    }
    sc[t] = scv;
    sh[t] = shv;
  }
  __syncthreads();
  int idx = blockIdx.x * 256 + t;
  int nc = idx >> 7, k = idx & 127;
  Wt[(size_t)nc * 128 + k] = f2bf(W[(size_t)k * 128 + nc] * sc[k]);
  if (blockIdx.x == 0 && t < 128) {
    float s = 0.f;
    if (use_affine) {
      for (int kk = 0; kk < 128; kk++) s += sh[kk] * W[(size_t)kk * 128 + t];
    }
    rbias[t] = s;
  }
}

// ---------------- MFMA GEMM (swapped operands, LDS-staged Wt) ----------------
// 128 rows per block: two sequential 64-row sub-tiles reuse the staged Wt
// (halves staging traffic + barrier count vs 64-row blocks).
template <int A_IS_FP32>
__global__ __launch_bounds__(256) void gemm_mfma_kernel(
    const void* __restrict__ Ain, const unsigned short* __restrict__ Wt,
    const float* __restrict__ rbias, const float* __restrict__ dinv,
    unsigned short* __restrict__ xb, int n) {
  __shared__ unsigned short wt[128 * WT_PITCH];
  int t = threadIdx.x;
  {  // stage Wt 128x128 bf16 -> LDS (padded pitch); 64 shorts = 8 uint4/thread
    int row = t >> 1, half = t & 1;
    const uint4* src = (const uint4*)(Wt + (size_t)row * 128 + half * 64);
    uint4* dst = (uint4*)(wt + row * WT_PITCH + half * 64);
#pragma unroll
    for (int j = 0; j < 8; j++) dst[j] = src[j];
  }
  __syncthreads();

  int l = t & 63;
  int w = t >> 6;
  int kg = l >> 4;

  for (int sub = 0; sub < 2; sub++) {
    int row0 = blockIdx.x * 128 + sub * 64 + w * 16;
    if (row0 >= n) break;
    int m = row0 + (l & 15);  // node row this lane owns
    int mc = m < n ? m : n - 1;

    // b-frags: this lane's node row, 4 x 16B (issued up front, independent)
    bf16x8 b[4];
#pragma unroll
    for (int kk = 0; kk < 4; kk++) {
      if (A_IS_FP32) {
        const float* ap = (const float*)Ain + (size_t)mc * 128 + kk * 32 + kg * 8;
        float4 f0 = *(const float4*)ap;
        float4 f1 = *(const float4*)(ap + 4);
        bf16x8 bb;
        bb[0] = (short)f2bf(f0.x); bb[1] = (short)f2bf(f0.y);
        bb[2] = (short)f2bf(f0.z); bb[3] = (short)f2bf(f0.w);
        bb[4] = (short)f2bf(f1.x); bb[5] = (short)f2bf(f1.y);
        bb[6] = (short)f2bf(f1.z); bb[7] = (short)f2bf(f1.w);
        b[kk] = bb;
      } else {
        b[kk] = *(const bf16x8*)((const unsigned short*)Ain + (size_t)mc * 128 + kk * 32 + kg * 8);
      }
    }

    f32x4 acc[8];
#pragma unroll
    for (int nt = 0; nt < 8; nt++) {
      f32x4 zv = {0.f, 0.f, 0.f, 0.f};
      acc[nt] = zv;
    }

#pragma unroll
    for (int kk = 0; kk < 4; kk++) {
#pragma unroll
      for (int nt = 0; nt < 8; nt++) {
        bf16x8 a = *(const bf16x8*)(wt + (size_t)(nt * 16 + (l & 15)) * WT_PITCH + kk * 32 + kg * 8);
        acc[nt] = __builtin_amdgcn_mfma_f32_16x16x32_bf16(a, b[kk], acc[nt], 0, 0, 0);
      }
    }

    float dv = dinv[mc];
    int colbase = kg * 4;
#pragma unroll
    for (int nt = 0; nt < 8; nt++) {
      int c0 = nt * 16 + colbase;
      float4 rb = *(const float4*)&rbias[c0];
      unsigned int w0 = pack2bf((acc[nt][0] + rb.x) * dv, (acc[nt][1] + rb.y) * dv);
      unsigned int w1 = pack2bf((acc[nt][2] + rb.z) * dv, (acc[nt][3] + rb.w) * dv);
      if (m < n)
        *(uint2*)(xb + (size_t)m * 128 + c0) = make_uint2(w0, w1);
    }
  }
}

// ---------------- aggregation: z[c] = dinv[c] * sum_in xb[row] ----------------
// Round-8-proven body: 16 lanes/node (uint4 = 8 bf16), unroll-4, early return,
// no barriers / no LDS. At the random-gather fabric limit (~6.4 TB/s line traffic).
template <int F32OUT>
__global__ __launch_bounds__(256) void agg_kernel(
    const uint4* __restrict__ x4, const int* __restrict__ csr_row,
    const int* __restrict__ offsets, const float* __restrict__ dinv,
    void* __restrict__ z, int n) {
  int node = blockIdx.x * 16 + (threadIdx.x >> 4);
  int d8 = threadIdx.x & 15;  // 8 bf16 per lane
  if (node >= n) return;
  int lo = offsets[node], hi = offsets[node + 1];
  float a0[8] = {}, a1[8] = {}, a2[8] = {}, a3[8] = {};
#define ACC8(A, v)                                                         \
  A[0] += __uint_as_float((v).x << 16); A[1] += __uint_as_float((v).x & 0xffff0000u); \
  A[2] += __uint_as_float((v).y << 16); A[3] += __uint_as_float((v).y & 0xffff0000u); \
  A[4] += __uint_as_float((v).z << 16); A[5] += __uint_as_float((v).z & 0xffff0000u); \
  A[6] += __uint_as_float((v).w << 16); A[7] += __uint_as_float((v).w & 0xffff0000u);
  int e = lo;
  for (; e + 4 <= hi; e += 4) {
    int r0 = csr_row[e];
    int r1 = csr_row[e + 1];
    int r2 = csr_row[e + 2];
    int r3 = csr_row[e + 3];
    uint4 v0 = x4[(size_t)r0 * 16 + d8];
    uint4 v1 = x4[(size_t)r1 * 16 + d8];
    uint4 v2 = x4[(size_t)r2 * 16 + d8];
    uint4 v3 = x4[(size_t)r3 * 16 + d8];
    ACC8(a0, v0) ACC8(a1, v1) ACC8(a2, v2) ACC8(a3, v3)
  }
  for (; e < hi; e++) {
    uint4 v = x4[(size_t)csr_row[e] * 16 + d8];
    ACC8(a0, v)
  }
#undef ACC8
  float dvn = dinv[node];
  float s[8];
#pragma unroll
  for (int j = 0; j < 8; j++) s[j] = (a0[j] + a1[j] + a2[j] + a3[j]) * dvn;
  if (F32OUT) {
    float* zp = (float*)z + (size_t)node * 128 + d8 * 8;
    *(float4*)zp = make_float4(s[0], s[1], s[2], s[3]);
    *(float4*)(zp + 4) = make_float4(s[4], s[5], s[6], s[7]);
  } else {
    uint4 o = make_uint4(pack2bf(s[0], s[1]), pack2bf(s[2], s[3]),
                         pack2bf(s[4], s[5]), pack2bf(s[6], s[7]));
    *(uint4*)((unsigned short*)z + (size_t)node * 128 + d8 * 8) = o;
  }
}

// ---------------- vectorized BN stats (streaming, balanced) ----------------
template <int F32IN>
__global__ __launch_bounds__(256) void stats2_kernel(
    const void* __restrict__ z, float* __restrict__ partial, int total8) {
  __shared__ float ps[256];  // [0:128) colsum, [128:256) colsumsq
  int t = threadIdx.x;
  ps[t] = 0.f;
  __syncthreads();
  int d8 = t & 15;
  float s[8] = {}, q[8] = {};
  int idx = blockIdx.x * 256 + t;
  int stride = gridDim.x * 256;  // multiple of 16 -> column group invariant
  for (int i = idx; i < total8; i += stride) {
    float v[8];
    if (F32IN) {
      const float* zp = (const float*)z + (size_t)i * 8;
      float4 f0 = *(const float4*)zp;
      float4 f1 = *(const float4*)(zp + 4);
      v[0] = f0.x; v[1] = f0.y; v[2] = f0.z; v[3] = f0.w;
      v[4] = f1.x; v[5] = f1.y; v[6] = f1.z; v[7] = f1.w;
    } else {
      uint4 u = ((const uint4*)z)[i];
      v[0] = __uint_as_float(u.x << 16); v[1] = __uint_as_float(u.x & 0xffff0000u);
      v[2] = __uint_as_float(u.y << 16); v[3] = __uint_as_float(u.y & 0xffff0000u);
      v[4] = __uint_as_float(u.z << 16); v[5] = __uint_as_float(u.z & 0xffff0000u);
      v[6] = __uint_as_float(u.w << 16); v[7] = __uint_as_float(u.w & 0xffff0000u);
    }
#pragma unroll
    for (int j = 0; j < 8; j++) { s[j] += v[j]; q[j] += v[j] * v[j]; }
  }
#pragma unroll
  for (int j = 0; j < 8; j++) {
    atomicAdd(&ps[d8 * 8 + j], s[j]);
    atomicAdd(&ps[128 + d8 * 8 + j], q[j]);
  }
  __syncthreads();
  partial[(size_t)blockIdx.x * 256 + t] = ps[t];
}

// reduce per-block partials -> colstats (colsum[0:128] ++ colsumsq[128:256])
__global__ __launch_bounds__(256) void reduce_stats_kernel(
    const float* __restrict__ partial, float* __restrict__ out, int nblk) {
  __shared__ float red[256];
  int c = blockIdx.x;  // 0..255
  float s = 0.f;
  for (int i = threadIdx.x; i < nblk; i += 256) s += partial[(size_t)i * 256 + c];
  red[threadIdx.x] = s;
  __syncthreads();
  for (int o = 128; o > 0; o >>= 1) {
    if (threadIdx.x < o) red[threadIdx.x] += red[threadIdx.x + o];
    __syncthreads();
  }
  if (threadIdx.x == 0) out[c] = red[0];
}

// in-place fp32 BN on d_out (layer 2): finalize folded in (per-block LDS)
__global__ __launch_bounds__(256) void norm_kernel(
    float* __restrict__ z, const float* __restrict__ colstats,
    const float* __restrict__ gamma, const float* __restrict__ beta,
    float invN, int total4) {
  __shared__ float sc[128], sh[128];
  int t = threadIdx.x;
  if (t < 128) {
    float mu = colstats[t] * invN;
    float var = colstats[128 + t] * invN - mu * mu;
    var = fmaxf(var, 0.f);
    float s = gamma[t] * rsqrtf(var + BN_EPS);
    sc[t] = s;
    sh[t] = beta[t] - mu * s;
  }
  __syncthreads();
  int idx = blockIdx.x * blockDim.x + t;
  int stride = gridDim.x * blockDim.x;
  for (int i = idx; i < total4; i += stride) {
    float4 v = ((const float4*)z)[i];
    int d0 = (i & 31) * 4;
    v.x = v.x * sc[d0] + sh[d0];
    v.y = v.y * sc[d0 + 1] + sh[d0 + 1];
    v.z = v.z * sc[d0 + 2] + sh[d0 + 2];
    v.w = v.w * sc[d0 + 3] + sh[d0 + 3];
    ((float4*)z)[i] = v;
  }
}

// ---------------- launcher ----------------

extern "C" void kernel_launch(void* const* d_in, const int* in_sizes, int n_in,
                              void* d_out, int out_size, void* d_ws, size_t ws_size,
                              hipStream_t stream) {
  const float* feats = (const float*)d_in[0];
  const void* edges = d_in[1];
  const float* W = (const float*)d_in[2];
  const float* gamma = (const float*)d_in[4];
  const float* beta = (const float*)d_in[5];

  const int n = in_sizes[0] / 128;
  const int E = in_sizes[1] / 2;

  const int nb = (n + 255) / 256;
  const int m = nb * NCHUNK;
  const int chunk = (E + NCHUNK - 1) / NCHUNK;
  const int sb_m = (m + 1023) / 1024;
  const int nagg = (n + 15) / 16;
  const int nstat = 1024;

  char* ws = (char*)d_ws;
  size_t off = 0;
  unsigned short* xb = (unsigned short*)(ws + off); off += (size_t)n * 128 * 2; off = (off + 255) & ~(size_t)255;
  float* dinv = (float*)(ws + off); off += (size_t)n * 4;
  int* offsets = (int*)(ws + off); off += (size_t)(n + 1) * 4; off = (off + 255) & ~(size_t)255;
  int* csr_row = (int*)(ws + off); off += (size_t)E * 4; off = (off + 255) & ~(size_t)255;
  int* pairs = (int*)(ws + off); off += (size_t)E * 4; off = (off + 255) & ~(size_t)255;
  int* blockcounts = (int*)(ws + off); off += (size_t)m * 4; off = (off + 255) & ~(size_t)255;
  int* moff = (int*)(ws + off); off += (size_t)(m + 1) * 4; off = (off + 255) & ~(size_t)255;
  int* tprefix = (int*)(ws + off); off += (size_t)sb_m * 256 * 4; off = (off + 255) & ~(size_t)255;
  int* bsum = (int*)(ws + off); off += 256 * 4;
  unsigned short* Wt = (unsigned short*)(ws + off); off += 128 * 128 * 2; off = (off + 255) & ~(size_t)255;
  float* rbias = (float*)(ws + off); off += 128 * 4;
  float* colstats = (float*)(ws + off); off += 256 * 4;
  int* mode = (int*)(ws + off); off += 4;

  // pairs is dead after CSR build; reuse as the stats-partial buffer (1 MB used)
  float* partial = (float*)pairs;

  // ---- contention-free CSR build (graph is layer-invariant) ----
  detect_kernel<<<1, 1, 0, stream>>>((const int*)edges, mode);
  count_kernel<<<NCHUNK, 256, 0, stream>>>(edges, mode, blockcounts, E, nb, chunk);
  scan1_kernel<<<sb_m, 256, 0, stream>>>(blockcounts, tprefix, bsum, m);
  scan2_kernel<<<1, 256, 0, stream>>>(bsum, sb_m, moff, m);
  scan3_kernel<<<sb_m, 256, 0, stream>>>(blockcounts, tprefix, bsum, moff, m);
  scatter_kernel<<<NCHUNK, 256, 0, stream>>>(edges, mode, moff, pairs, E, nb, chunk);
  passB12_kernel<<<nb, 256, 0, stream>>>(pairs, moff, dinv, offsets, csr_row, n);

  unsigned short* zb = (unsigned short*)d_out;  // bf16 z (layers 0,1)
  float* zf = (float*)d_out;                    // fp32 z (layer 2)
  const int ggrid = (n + 127) / 128;
  const int total8 = n * 16;
  const float invN = 1.0f / (float)n;

  for (int l = 0; l < 3; l++) {
    prepWR_kernel<<<64, 256, 0, stream>>>(W + (size_t)l * 16384, colstats,
                                          gamma + l * 128, beta + l * 128, invN,
                                          l > 0 ? 1 : 0, Wt, rbias);
    if (l == 0)
      gemm_mfma_kernel<1><<<ggrid, 256, 0, stream>>>(feats, Wt, rbias, dinv, xb, n);
    else
      gemm_mfma_kernel<0><<<ggrid, 256, 0, stream>>>(zb, Wt, rbias, dinv, xb, n);
    if (l < 2) {
      agg_kernel<0><<<nagg, 256, 0, stream>>>(
          (const uint4*)xb, csr_row, offsets, dinv, zb, n);
      stats2_kernel<0><<<nstat, 256, 0, stream>>>(zb, partial, total8);
    } else {
      agg_kernel<1><<<nagg, 256, 0, stream>>>(
          (const uint4*)xb, csr_row, offsets, dinv, zf, n);
      stats2_kernel<1><<<nstat, 256, 0, stream>>>(zf, partial, total8);
    }
    reduce_stats_kernel<<<256, 256, 0, stream>>>(partial, colstats, nstat);
  }
  norm_kernel<<<2048, 256, 0, stream>>>(zf, colstats, gamma + 2 * 128, beta + 2 * 128,
                                        invN, (n * 128) / 4);
}

// Round 15
// 412.975 us; speedup vs baseline: 1.0591x; 1.0109x over previous
//
#include <hip/hip_runtime.h>
#include <cstdint>
#include <cstddef>

#define BN_EPS 1e-5f
#define NCHUNK 256   // blocks in the edge-chunk partition (counting sort)
#define WT_PITCH 136 // bf16 elems per LDS Wt row (272B: 16B-aligned, bank-padded)

typedef short bf16x8 __attribute__((ext_vector_type(8)));
typedef float f32x4 __attribute__((ext_vector_type(4)));

// ---------------- helpers ----------------

__device__ __forceinline__ int edge_at(const void* e, long long i, int m64) {
  return m64 ? (int)((const long long*)e)[i] : ((const int*)e)[i];
}

__device__ __forceinline__ unsigned short f2bf(float f) {
  unsigned int u = __float_as_uint(f);
  unsigned int r = (u + 0x7FFFu + ((u >> 16) & 1u)) >> 16;
  return (unsigned short)r;
}

__device__ __forceinline__ unsigned int pack2bf(float lo, float hi) {
  return (unsigned int)f2bf(lo) | ((unsigned int)f2bf(hi) << 16);
}

// int64 vs int32 edge detection, inlined per block (indices < 2^31 -> for
// int64 data every odd 32-bit word is 0).
__device__ __forceinline__ int detect_mode_thread0(const int* e32) {
  int nz = 0;
  for (int i = 1; i < 512; i += 2) nz |= e32[i];
  return (nz == 0) ? 1 : 0;
}

// ---------------- contention-free counting sort by bucket ----------------

__global__ __launch_bounds__(256) void count_kernel(const void* __restrict__ edges,
                                                    int* __restrict__ blockcounts,
                                                    int E, int nb, int chunk) {
  __shared__ int h[1024];
  __shared__ int smode;
  for (int i = threadIdx.x; i < nb; i += 256) h[i] = 0;
  if (threadIdx.x == 0) smode = detect_mode_thread0((const int*)edges);
  __syncthreads();
  int m = smode;
  long long lo = (long long)blockIdx.x * chunk;
  long long hi = lo + chunk;
  if (hi > E) hi = E;
  for (long long i = lo + threadIdx.x; i < hi; i += 256) {
    int c = edge_at(edges, (long long)E + i, m);
    atomicAdd(&h[c >> 8], 1);
  }
  __syncthreads();
  for (int j = threadIdx.x; j < nb; j += 256)
    blockcounts[(size_t)j * NCHUNK + blockIdx.x] = h[j];
}

// ---- generic hierarchical exclusive scan (4 elems/thread), used for moff ----
__global__ __launch_bounds__(256) void scan1_kernel(const int* __restrict__ src,
                                                    int* __restrict__ tprefix,
                                                    int* __restrict__ bsum, int n) {
  __shared__ int s[256];
  int t = threadIdx.x;
  int gid = blockIdx.x * 256 + t;
  int base = gid * 4;
  int sum = 0;
#pragma unroll
  for (int j = 0; j < 4; j++) {
    int i = base + j;
    if (i < n) sum += src[i];
  }
  s[t] = sum;
  __syncthreads();
  for (int off = 1; off < 256; off <<= 1) {
    int v = (t >= off) ? s[t - off] : 0;
    __syncthreads();
    s[t] += v;
    __syncthreads();
  }
  tprefix[gid] = s[t] - sum;
  if (t == 255) bsum[blockIdx.x] = s[255];
}

__global__ __launch_bounds__(256) void scan2_kernel(int* __restrict__ bsum, int nbk,
                                                    int* __restrict__ out, int n) {
  __shared__ int s[256];
  int t = threadIdx.x;
  int v = (t < nbk) ? bsum[t] : 0;
  s[t] = v;
  __syncthreads();
  for (int off = 1; off < 256; off <<= 1) {
    int u = (t >= off) ? s[t - off] : 0;
    __syncthreads();
    s[t] += u;
    __syncthreads();
  }
  if (t < nbk) bsum[t] = s[t] - v;
  if (t == 255) out[n] = s[255];
}

__global__ __launch_bounds__(256) void scan3_kernel(const int* __restrict__ src,
                                                    const int* __restrict__ tprefix,
                                                    const int* __restrict__ bsum,
                                                    int* __restrict__ out, int n) {
  int gid = blockIdx.x * 256 + threadIdx.x;
  int run = bsum[blockIdx.x] + tprefix[gid];
  int base = gid * 4;
#pragma unroll
  for (int j = 0; j < 4; j++) {
    int i = base + j;
    if (i < n) {
      int c = src[i];
      out[i] = run;
      run += c;
    }
  }
}

__global__ __launch_bounds__(256) void scatter_kernel(const void* __restrict__ edges,
                                                      const int* __restrict__ moff,
                                                      int* __restrict__ pairs,
                                                      int E, int nb, int chunk) {
  __shared__ int cur[1024];
  __shared__ int smode;
  for (int j = threadIdx.x; j < nb; j += 256)
    cur[j] = moff[(size_t)j * NCHUNK + blockIdx.x];
  if (threadIdx.x == 0) smode = detect_mode_thread0((const int*)edges);
  __syncthreads();
  int m = smode;
  long long lo = (long long)blockIdx.x * chunk;
  long long hi = lo + chunk;
  if (hi > E) hi = E;
  for (long long i = lo + threadIdx.x; i < hi; i += 256) {
    int r = edge_at(edges, i, m);
    int c = edge_at(edges, (long long)E + i, m);
    int pos = atomicAdd(&cur[c >> 8], 1);
    pairs[pos] = (r << 8) | (c & 255);
  }
}

// merged per-bucket finalize: histogram -> dinv + offsets -> CSR fill
__global__ __launch_bounds__(256) void passB12_kernel(const int* __restrict__ pairs,
                                                      const int* __restrict__ moff,
                                                      float* __restrict__ dinv,
                                                      int* __restrict__ offsets,
                                                      int* __restrict__ csr_row, int n) {
  __shared__ int h[256];
  __shared__ int s[256];
  int t = threadIdx.x;
  int b = blockIdx.x;
  h[t] = 0;
  __syncthreads();
  int lo = moff[(size_t)b * NCHUNK];
  int hi = moff[(size_t)(b + 1) * NCHUNK];
  for (int e = lo + t; e < hi; e += 256)
    atomicAdd(&h[pairs[e] & 255], 1);
  __syncthreads();
  int d = h[t];
  s[t] = d;
  __syncthreads();
  for (int off = 1; off < 256; off <<= 1) {
    int v = (t >= off) ? s[t - off] : 0;
    __syncthreads();
    s[t] += v;
    __syncthreads();
  }
  int start = lo + s[t] - d;
  int node = b * 256 + t;
  if (node < n) {
    offsets[node] = start;
    dinv[node] = d > 0 ? rsqrtf((float)d) : 0.f;
    if (node == n - 1) offsets[n] = hi;
  }
  s[t] = start;  // reuse as cursor
  __syncthreads();
  for (int e = lo + t; e < hi; e += 256) {
    int p = pairs[e];
    int pos = atomicAdd(&s[p & 255], 1);
    csr_row[pos] = p >> 8;
  }
}

// ---------------- per-layer prep: BN finalize + fold affine into W ----------------
__global__ __launch_bounds__(256) void prepWR_kernel(const float* __restrict__ W,
                                                     const float* __restrict__ colstats,
                                                     const float* __restrict__ gamma,
                                                     const float* __restrict__ beta,
                                                     float invN, int use_affine,
                                                     unsigned short* __restrict__ Wt,
                                                     float* __restrict__ rbias) {
  __shared__ float sc[128], sh[128];
  int t = threadIdx.x;
  if (t < 128) {
    float scv = 1.f, shv = 0.f;
    if (use_affine) {
      float mu = colstats[t] * invN;
      float var = colstats[128 + t] * invN - mu * mu;
      var = fmaxf(var, 0.f);
      scv = gamma[t] * rsqrtf(var + BN_EPS);
      shv = beta[t] - mu * scv;
    }
    sc[t] = scv;
    sh[t] = shv;
  }
  __syncthreads();
  int idx = blockIdx.x * 256 + t;
  int nc = idx >> 7, k = idx & 127;
  Wt[(size_t)nc * 128 + k] = f2bf(W[(size_t)k * 128 + nc] * sc[k]);
  if (blockIdx.x == 0 && t < 128) {
    float s = 0.f;
    if (use_affine) {
      for (int kk = 0; kk < 128; kk++) s += sh[kk] * W[(size_t)kk * 128 + t];
    }
    rbias[t] = s;
  }
}

// ---------------- MFMA GEMM (swapped operands, LDS-staged Wt) ----------------
// 128 rows/block (two 64-row sub-tiles reuse staged Wt); sub-0 b-frag loads
// issued BEFORE staging so the global reads overlap stage+barrier.

template <int A_IS_FP32>
__device__ __forceinline__ void gemm_load_b(const void* Ain, int mc, int kg, bf16x8* b) {
#pragma unroll
  for (int kk = 0; kk < 4; kk++) {
    if (A_IS_FP32) {
      const float* ap = (const float*)Ain + (size_t)mc * 128 + kk * 32 + kg * 8;
      float4 f0 = *(const float4*)ap;
      float4 f1 = *(const float4*)(ap + 4);
      bf16x8 bb;
      bb[0] = (short)f2bf(f0.x); bb[1] = (short)f2bf(f0.y);
      bb[2] = (short)f2bf(f0.z); bb[3] = (short)f2bf(f0.w);
      bb[4] = (short)f2bf(f1.x); bb[5] = (short)f2bf(f1.y);
      bb[6] = (short)f2bf(f1.z); bb[7] = (short)f2bf(f1.w);
      b[kk] = bb;
    } else {
      b[kk] = *(const bf16x8*)((const unsigned short*)Ain + (size_t)mc * 128 + kk * 32 + kg * 8);
    }
  }
}

__device__ __forceinline__ void gemm_compute_store(
    const unsigned short* wt, const bf16x8* b, const float* rbias,
    const float* dinv, unsigned short* xb, int m, int mc, int l, int kg, int n) {
  f32x4 acc[8];
#pragma unroll
  for (int nt = 0; nt < 8; nt++) {
    f32x4 zv = {0.f, 0.f, 0.f, 0.f};
    acc[nt] = zv;
  }
#pragma unroll
  for (int kk = 0; kk < 4; kk++) {
#pragma unroll
    for (int nt = 0; nt < 8; nt++) {
      bf16x8 a = *(const bf16x8*)(wt + (size_t)(nt * 16 + (l & 15)) * WT_PITCH + kk * 32 + kg * 8);
      acc[nt] = __builtin_amdgcn_mfma_f32_16x16x32_bf16(a, b[kk], acc[nt], 0, 0, 0);
    }
  }
  float dv = dinv[mc];
  int colbase = kg * 4;
#pragma unroll
  for (int nt = 0; nt < 8; nt++) {
    int c0 = nt * 16 + colbase;
    float4 rb = *(const float4*)&rbias[c0];
    unsigned int w0 = pack2bf((acc[nt][0] + rb.x) * dv, (acc[nt][1] + rb.y) * dv);
    unsigned int w1 = pack2bf((acc[nt][2] + rb.z) * dv, (acc[nt][3] + rb.w) * dv);
    if (m < n)
      *(uint2*)(xb + (size_t)m * 128 + c0) = make_uint2(w0, w1);
  }
}

template <int A_IS_FP32>
__global__ __launch_bounds__(256) void gemm_mfma_kernel(
    const void* __restrict__ Ain, const unsigned short* __restrict__ Wt,
    const float* __restrict__ rbias, const float* __restrict__ dinv,
    unsigned short* __restrict__ xb, int n) {
  __shared__ unsigned short wt[128 * WT_PITCH];
  int t = threadIdx.x;
  int l = t & 63;
  int w = t >> 6;
  int kg = l >> 4;

  // sub-0 b-frags first: global loads overlap the LDS staging + barrier
  int row0 = blockIdx.x * 128 + w * 16;
  int m0 = row0 + (l & 15);
  int mc0 = m0 < n ? m0 : n - 1;
  bf16x8 b[4];
  gemm_load_b<A_IS_FP32>(Ain, mc0, kg, b);

  {  // stage Wt 128x128 bf16 -> LDS (padded pitch); 64 shorts = 8 uint4/thread
    int row = t >> 1, half = t & 1;
    const uint4* src = (const uint4*)(Wt + (size_t)row * 128 + half * 64);
    uint4* dst = (uint4*)(wt + row * WT_PITCH + half * 64);
#pragma unroll
    for (int j = 0; j < 8; j++) dst[j] = src[j];
  }
  __syncthreads();

  if (row0 < n)
    gemm_compute_store(wt, b, rbias, dinv, xb, m0, mc0, l, kg, n);

  int row1 = row0 + 64;
  if (row1 < n) {
    int m1 = m0 + 64;
    int mc1 = m1 < n ? m1 : n - 1;
    gemm_load_b<A_IS_FP32>(Ain, mc1, kg, b);
    gemm_compute_store(wt, b, rbias, dinv, xb, m1, mc1, l, kg, n);
  }
}

// ---------------- aggregation: z[c] = dinv[c] * sum_in xb[row] ----------------
// Round-8-proven body: 16 lanes/node (uint4 = 8 bf16), unroll-4, early return,
// no barriers / no LDS. At the random-gather fabric service limit (~6.4 TB/s).
template <int F32OUT>
__global__ __launch_bounds__(256) void agg_kernel(
    const uint4* __restrict__ x4, const int* __restrict__ csr_row,
    const int* __restrict__ offsets, const float* __restrict__ dinv,
    void* __restrict__ z, int n) {
  int node = blockIdx.x * 16 + (threadIdx.x >> 4);
  int d8 = threadIdx.x & 15;  // 8 bf16 per lane
  if (node >= n) return;
  int lo = offsets[node], hi = offsets[node + 1];
  float a0[8] = {}, a1[8] = {}, a2[8] = {}, a3[8] = {};
#define ACC8(A, v)                                                         \
  A[0] += __uint_as_float((v).x << 16); A[1] += __uint_as_float((v).x & 0xffff0000u); \
  A[2] += __uint_as_float((v).y << 16); A[3] += __uint_as_float((v).y & 0xffff0000u); \
  A[4] += __uint_as_float((v).z << 16); A[5] += __uint_as_float((v).z & 0xffff0000u); \
  A[6] += __uint_as_float((v).w << 16); A[7] += __uint_as_float((v).w & 0xffff0000u);
  int e = lo;
  for (; e + 4 <= hi; e += 4) {
    int r0 = csr_row[e];
    int r1 = csr_row[e + 1];
    int r2 = csr_row[e + 2];
    int r3 = csr_row[e + 3];
    uint4 v0 = x4[(size_t)r0 * 16 + d8];
    uint4 v1 = x4[(size_t)r1 * 16 + d8];
    uint4 v2 = x4[(size_t)r2 * 16 + d8];
    uint4 v3 = x4[(size_t)r3 * 16 + d8];
    ACC8(a0, v0) ACC8(a1, v1) ACC8(a2, v2) ACC8(a3, v3)
  }
  for (; e < hi; e++) {
    uint4 v = x4[(size_t)csr_row[e] * 16 + d8];
    ACC8(a0, v)
  }
#undef ACC8
  float dvn = dinv[node];
  float s[8];
#pragma unroll
  for (int j = 0; j < 8; j++) s[j] = (a0[j] + a1[j] + a2[j] + a3[j]) * dvn;
  if (F32OUT) {
    float* zp = (float*)z + (size_t)node * 128 + d8 * 8;
    *(float4*)zp = make_float4(s[0], s[1], s[2], s[3]);
    *(float4*)(zp + 4) = make_float4(s[4], s[5], s[6], s[7]);
  } else {
    uint4 o = make_uint4(pack2bf(s[0], s[1]), pack2bf(s[2], s[3]),
                         pack2bf(s[4], s[5]), pack2bf(s[6], s[7]));
    *(uint4*)((unsigned short*)z + (size_t)node * 128 + d8 * 8) = o;
  }
}

// ---------------- vectorized BN stats (streaming, balanced) ----------------
template <int F32IN>
__global__ __launch_bounds__(256) void stats2_kernel(
    const void* __restrict__ z, float* __restrict__ partial, int total8) {
  __shared__ float ps[256];  // [0:128) colsum, [128:256) colsumsq
  int t = threadIdx.x;
  ps[t] = 0.f;
  __syncthreads();
  int d8 = t & 15;
  float s[8] = {}, q[8] = {};
  int idx = blockIdx.x * 256 + t;
  int stride = gridDim.x * 256;  // multiple of 16 -> column group invariant
  for (int i = idx; i < total8; i += stride) {
    float v[8];
    if (F32IN) {
      const float* zp = (const float*)z + (size_t)i * 8;
      float4 f0 = *(const float4*)zp;
      float4 f1 = *(const float4*)(zp + 4);
      v[0] = f0.x; v[1] = f0.y; v[2] = f0.z; v[3] = f0.w;
      v[4] = f1.x; v[5] = f1.y; v[6] = f1.z; v[7] = f1.w;
    } else {
      uint4 u = ((const uint4*)z)[i];
      v[0] = __uint_as_float(u.x << 16); v[1] = __uint_as_float(u.x & 0xffff0000u);
      v[2] = __uint_as_float(u.y << 16); v[3] = __uint_as_float(u.y & 0xffff0000u);
      v[4] = __uint_as_float(u.z << 16); v[5] = __uint_as_float(u.z & 0xffff0000u);
      v[6] = __uint_as_float(u.w << 16); v[7] = __uint_as_float(u.w & 0xffff0000u);
    }
#pragma unroll
    for (int j = 0; j < 8; j++) { s[j] += v[j]; q[j] += v[j] * v[j]; }
  }
#pragma unroll
  for (int j = 0; j < 8; j++) {
    atomicAdd(&ps[d8 * 8 + j], s[j]);
    atomicAdd(&ps[128 + d8 * 8 + j], q[j]);
  }
  __syncthreads();
  partial[(size_t)blockIdx.x * 256 + t] = ps[t];
}

// reduce per-block partials -> colstats (colsum[0:128] ++ colsumsq[128:256])
__global__ __launch_bounds__(256) void reduce_stats_kernel(
    const float* __restrict__ partial, float* __restrict__ out, int nblk) {
  __shared__ float red[256];
  int c = blockIdx.x;  // 0..255
  float s = 0.f;
  for (int i = threadIdx.x; i < nblk; i += 256) s += partial[(size_t)i * 256 + c];
  red[threadIdx.x] = s;
  __syncthreads();
  for (int o = 128; o > 0; o >>= 1) {
    if (threadIdx.x < o) red[threadIdx.x] += red[threadIdx.x + o];
    __syncthreads();
  }
  if (threadIdx.x == 0) out[c] = red[0];
}

// in-place fp32 BN on d_out (layer 2, fp32-z fallback path)
__global__ __launch_bounds__(256) void norm_kernel(
    float* __restrict__ z, const float* __restrict__ colstats,
    const float* __restrict__ gamma, const float* __restrict__ beta,
    float invN, int total4) {
  __shared__ float sc[128], sh[128];
  int t = threadIdx.x;
  if (t < 128) {
    float mu = colstats[t] * invN;
    float var = colstats[128 + t] * invN - mu * mu;
    var = fmaxf(var, 0.f);
    float s = gamma[t] * rsqrtf(var + BN_EPS);
    sc[t] = s;
    sh[t] = beta[t] - mu * s;
  }
  __syncthreads();
  int idx = blockIdx.x * blockDim.x + t;
  int stride = gridDim.x * blockDim.x;
  for (int i = idx; i < total4; i += stride) {
    float4 v = ((const float4*)z)[i];
    int d0 = (i & 31) * 4;
    v.x = v.x * sc[d0] + sh[d0];
    v.y = v.y * sc[d0 + 1] + sh[d0 + 1];
    v.z = v.z * sc[d0 + 2] + sh[d0 + 2];
    v.w = v.w * sc[d0 + 3] + sh[d0 + 3];
    ((float4*)z)[i] = v;
  }
}

// BN from bf16 z (ws buffer) -> fp32 d_out (no aliasing)
__global__ __launch_bounds__(256) void norm_bf16_kernel(
    const unsigned short* __restrict__ zb, float* __restrict__ out,
    const float* __restrict__ colstats, const float* __restrict__ gamma,
    const float* __restrict__ beta, float invN, int total4) {
  __shared__ float sc[128], sh[128];
  int t = threadIdx.x;
  if (t < 128) {
    float mu = colstats[t] * invN;
    float var = colstats[128 + t] * invN - mu * mu;
    var = fmaxf(var, 0.f);
    float s = gamma[t] * rsqrtf(var + BN_EPS);
    sc[t] = s;
    sh[t] = beta[t] - mu * s;
  }
  __syncthreads();
  int idx = blockIdx.x * blockDim.x + t;
  int stride = gridDim.x * blockDim.x;
  for (int i = idx; i < total4; i += stride) {
    uint2 u = *(const uint2*)(zb + (size_t)i * 4);
    int d0 = (i & 31) * 4;
    float4 v;
    v.x = __uint_as_float(u.x << 16) * sc[d0] + sh[d0];
    v.y = __uint_as_float(u.x & 0xffff0000u) * sc[d0 + 1] + sh[d0 + 1];
    v.z = __uint_as_float(u.y << 16) * sc[d0 + 2] + sh[d0 + 2];
    v.w = __uint_as_float(u.y & 0xffff0000u) * sc[d0 + 3] + sh[d0 + 3];
    ((float4*)out)[i] = v;
  }
}

// ---------------- launcher ----------------

extern "C" void kernel_launch(void* const* d_in, const int* in_sizes, int n_in,
                              void* d_out, int out_size, void* d_ws, size_t ws_size,
                              hipStream_t stream) {
  const float* feats = (const float*)d_in[0];
  const void* edges = d_in[1];
  const float* W = (const float*)d_in[2];
  const float* gamma = (const float*)d_in[4];
  const float* beta = (const float*)d_in[5];

  const int n = in_sizes[0] / 128;
  const int E = in_sizes[1] / 2;

  const int nb = (n + 255) / 256;
  const int m = nb * NCHUNK;
  const int chunk = (E + NCHUNK - 1) / NCHUNK;
  const int sb_m = (m + 1023) / 1024;
  const int nagg = (n + 15) / 16;
  const int nstat = 1024;

  char* ws = (char*)d_ws;
  size_t off = 0;
  unsigned short* xb = (unsigned short*)(ws + off); off += (size_t)n * 128 * 2; off = (off + 255) & ~(size_t)255;
  float* dinv = (float*)(ws + off); off += (size_t)n * 4;
  int* offsets = (int*)(ws + off); off += (size_t)(n + 1) * 4; off = (off + 255) & ~(size_t)255;
  int* csr_row = (int*)(ws + off); off += (size_t)E * 4; off = (off + 255) & ~(size_t)255;
  int* pairs = (int*)(ws + off); off += (size_t)E * 4; off = (off + 255) & ~(size_t)255;
  int* blockcounts = (int*)(ws + off); off += (size_t)m * 4; off = (off + 255) & ~(size_t)255;
  int* moff = (int*)(ws + off); off += (size_t)(m + 1) * 4; off = (off + 255) & ~(size_t)255;
  int* tprefix = (int*)(ws + off); off += (size_t)sb_m * 256 * 4; off = (off + 255) & ~(size_t)255;
  int* bsum = (int*)(ws + off); off += 256 * 4;
  unsigned short* Wt = (unsigned short*)(ws + off); off += 128 * 128 * 2; off = (off + 255) & ~(size_t)255;
  float* rbias = (float*)(ws + off); off += 128 * 4;
  float* colstats = (float*)(ws + off); off += 256 * 4; off = (off + 255) & ~(size_t)255;
  // optional bf16 z buffer for layer 2 (runtime ws_size gate; fp32 fallback)
  unsigned short* zb2 = (unsigned short*)(ws + off);
  const int use_bf16z = (off + (size_t)n * 128 * 2 <= ws_size) ? 1 : 0;

  // pairs is dead after CSR build; reuse as the stats-partial buffer (1 MB used)
  float* partial = (float*)pairs;

  // ---- contention-free CSR build (graph is layer-invariant) ----
  count_kernel<<<NCHUNK, 256, 0, stream>>>(edges, blockcounts, E, nb, chunk);
  scan1_kernel<<<sb_m, 256, 0, stream>>>(blockcounts, tprefix, bsum, m);
  scan2_kernel<<<1, 256, 0, stream>>>(bsum, sb_m, moff, m);
  scan3_kernel<<<sb_m, 256, 0, stream>>>(blockcounts, tprefix, bsum, moff, m);
  scatter_kernel<<<NCHUNK, 256, 0, stream>>>(edges, moff, pairs, E, nb, chunk);
  passB12_kernel<<<nb, 256, 0, stream>>>(pairs, moff, dinv, offsets, csr_row, n);

  unsigned short* zb = (unsigned short*)d_out;  // bf16 z (layers 0,1)
  float* zf = (float*)d_out;                    // fp32 z / final out
  const int ggrid = (n + 127) / 128;
  const int total8 = n * 16;
  const int total4 = (n * 128) / 4;
  const float invN = 1.0f / (float)n;

  for (int l = 0; l < 3; l++) {
    prepWR_kernel<<<64, 256, 0, stream>>>(W + (size_t)l * 16384, colstats,
                                          gamma + l * 128, beta + l * 128, invN,
                                          l > 0 ? 1 : 0, Wt, rbias);
    if (l == 0)
      gemm_mfma_kernel<1><<<ggrid, 256, 0, stream>>>(feats, Wt, rbias, dinv, xb, n);
    else
      gemm_mfma_kernel<0><<<ggrid, 256, 0, stream>>>(zb, Wt, rbias, dinv, xb, n);
    if (l < 2) {
      agg_kernel<0><<<nagg, 256, 0, stream>>>(
          (const uint4*)xb, csr_row, offsets, dinv, zb, n);
      stats2_kernel<0><<<nstat, 256, 0, stream>>>(zb, partial, total8);
    } else if (use_bf16z) {
      agg_kernel<0><<<nagg, 256, 0, stream>>>(
          (const uint4*)xb, csr_row, offsets, dinv, zb2, n);
      stats2_kernel<0><<<nstat, 256, 0, stream>>>(zb2, partial, total8);
    } else {
      agg_kernel<1><<<nagg, 256, 0, stream>>>(
          (const uint4*)xb, csr_row, offsets, dinv, zf, n);
      stats2_kernel<1><<<nstat, 256, 0, stream>>>(zf, partial, total8);
    }
    reduce_stats_kernel<<<256, 256, 0, stream>>>(partial, colstats, nstat);
  }
  if (use_bf16z)
    norm_bf16_kernel<<<2048, 256, 0, stream>>>(zb2, zf, colstats, gamma + 2 * 128,
                                               beta + 2 * 128, invN, total4);
  else
    norm_kernel<<<2048, 256, 0, stream>>>(zf, colstats, gamma + 2 * 128,
                                          beta + 2 * 128, invN, total4);
}